// Round 5
// baseline (887.642 us; speedup 1.0000x reference)
//
#include <hip/hip_runtime.h>

#define LEAKY 0.2f

__device__ __forceinline__ float bf2f(unsigned short u) {
    return __uint_as_float(((unsigned)u) << 16);
}
__device__ __forceinline__ unsigned short f2bf(float f) {
    unsigned u = __float_as_uint(f);
    unsigned r = (u + 0x7fffu + ((u >> 16) & 1u)) >> 16;  // RNE
    return (unsigned short)r;
}
// NaN-propagating relu (NaN fails v<0 -> NaN survives -> diagnosable)
__device__ __forceinline__ float relu_nan(float v) { return v < 0.0f ? 0.0f : v; }

// ---------- K_fill: fp32-fill output (ws-too-small diagnosis: absmax ~= ws MB) ----------
__global__ void k_fill(float* __restrict__ p, float val, int n) {
    int i = blockIdx.x * blockDim.x + threadIdx.x;
    if (i < n) p[i] = val;
}

// ---------- K_zero ----------
__global__ void k_zero(int* __restrict__ cnt, int n) {
    int i = blockIdx.x * blockDim.x + threadIdx.x;
    if (i < n) cnt[i] = 0;
}

// ---------- K1: h = X @ W_n (per-head, fp32) + node scores s_src/s_dst ----------
// block = 256: 16 rows x 256 cols, 4x4 microtile per thread. h stored bf16.
__global__ __launch_bounds__(256) void k_transform(
    const float* __restrict__ X, const float* __restrict__ Wn,
    const float* __restrict__ Asrc, const float* __restrict__ Adst,
    unsigned short* __restrict__ h_out, float* __restrict__ s_src, float* __restrict__ s_dst) {
    __shared__ float xt[16][132];
    const int t = threadIdx.x;
    const int row0 = blockIdx.x * 16;

    for (int i = t; i < 16 * 32; i += 256) {   // 16 rows x 32 float4
        int r = i >> 5, cp = i & 31;
        float4 v = ((const float4*)(X + (size_t)(row0 + r) * 128))[cp];
        xt[r][cp * 4 + 0] = v.x; xt[r][cp * 4 + 1] = v.y;
        xt[r][cp * 4 + 2] = v.z; xt[r][cp * 4 + 3] = v.w;
    }
    __syncthreads();

    const int r0 = (t >> 6) << 2;
    const int j0 = (t & 63) << 2;
    const int head = j0 >> 6;
    const int dd = j0 & 63;
    const float* wbase = Wn + (size_t)head * 128 * 64 + dd;

    float acc[4][4] = {};
    for (int c = 0; c < 128; ++c) {
        float4 wv = *(const float4*)(wbase + (size_t)c * 64);
        float x0 = xt[r0 + 0][c], x1 = xt[r0 + 1][c], x2 = xt[r0 + 2][c], x3 = xt[r0 + 3][c];
        acc[0][0] += x0 * wv.x; acc[0][1] += x0 * wv.y; acc[0][2] += x0 * wv.z; acc[0][3] += x0 * wv.w;
        acc[1][0] += x1 * wv.x; acc[1][1] += x1 * wv.y; acc[1][2] += x1 * wv.z; acc[1][3] += x1 * wv.w;
        acc[2][0] += x2 * wv.x; acc[2][1] += x2 * wv.y; acc[2][2] += x2 * wv.z; acc[2][3] += x2 * wv.w;
        acc[3][0] += x3 * wv.x; acc[3][1] += x3 * wv.y; acc[3][2] += x3 * wv.z; acc[3][3] += x3 * wv.w;
    }

    for (int rr = 0; rr < 4; ++rr) {
        ushort4 o;
        o.x = f2bf(acc[rr][0]); o.y = f2bf(acc[rr][1]);
        o.z = f2bf(acc[rr][2]); o.w = f2bf(acc[rr][3]);
        *(ushort4*)(h_out + (size_t)(row0 + r0 + rr) * 256 + j0) = o;
    }

    float4 as4 = *(const float4*)(Asrc + head * 64 + dd);
    float4 ad4 = *(const float4*)(Adst + head * 64 + dd);
    for (int rr = 0; rr < 4; ++rr) {
        float ps = acc[rr][0] * as4.x + acc[rr][1] * as4.y + acc[rr][2] * as4.z + acc[rr][3] * as4.w;
        float pd = acc[rr][0] * ad4.x + acc[rr][1] * ad4.y + acc[rr][2] * ad4.z + acc[rr][3] * ad4.w;
        for (int m = 1; m < 16; m <<= 1) {
            ps += __shfl_xor(ps, m, 64);
            pd += __shfl_xor(pd, m, 64);
        }
        if ((t & 15) == 0) {
            s_src[(row0 + r0 + rr) * 4 + head] = ps;
            s_dst[(row0 + r0 + rr) * 4 + head] = pd;
        }
    }
}

// ---------- K2: histogram of dst degrees ----------
__global__ void k_hist(const int* __restrict__ dst, int* __restrict__ cnt, int E) {
    int e = blockIdx.x * blockDim.x + threadIdx.x;
    if (e < E) atomicAdd(cnt + dst[e], 1);
}

// ---------- K3: exclusive prefix scan (single wave, shuffle-based) ----------
__global__ void k_scan(const int* __restrict__ cnt, int* __restrict__ rowptr,
                       int* __restrict__ wcnt, int N, int E) {
    const int lane = threadIdx.x;  // 64 threads, 1 block
    int carry = 0;
    for (int base = 0; base < N; base += 64) {
        int i = base + lane;
        int v = (i < N) ? cnt[i] : 0;
        int x = v;
        for (int off = 1; off < 64; off <<= 1) {
            int y = __shfl_up(x, off, 64);
            if (lane >= off) x += y;
        }
        int excl = carry + x - v;
        if (i < N) { rowptr[i] = excl; wcnt[i] = excl; }
        carry += __shfl(x, 63, 64);
    }
    if (lane == 0) rowptr[N] = E;
}

// ---------- K4: scatter src ids into CSR order ----------
__global__ void k_scatter(const int* __restrict__ src, const int* __restrict__ dst,
                          int* __restrict__ wcnt, int* __restrict__ esrc, int E) {
    int e = blockIdx.x * blockDim.x + threadIdx.x;
    if (e < E) {
        int pos = atomicAdd(wcnt + dst[e], 1);
        esrc[pos] = src[e];
    }
}

// ---------- K5: per-dst gather-aggregate (registers only) + fused 2-layer MLP ----------
// Block = 16 dst nodes. Wave w handles rows 4w..4w+3; lane l covers dims 4l..4l+3
// (head = l>>4). Per 16-edge chunk: lane l computes ex for (edge l&15, head l>>4);
// exchanged via __shfl — no LDS traffic, no barriers in the gather loop.
__global__ __launch_bounds__(256) void k_agg_mlp(
    const float* __restrict__ s_src, const float* __restrict__ s_dst,
    const unsigned short* __restrict__ h_bf,
    const int* __restrict__ rowptr, const int* __restrict__ esrc,
    const float* __restrict__ mW1, const float* __restrict__ mb1,
    const float* __restrict__ mW2, const float* __restrict__ mb2,
    float* __restrict__ out) {
    __shared__ float ct[16][260];
    __shared__ float ht[16][260];
    const int t = threadIdx.x;
    const int lane = t & 63;
    const int wave = t >> 6;
    const int row0 = blockIdx.x * 16;
    const int head = lane >> 4;
    const int c0 = lane << 2;
    const int eslot = lane & 15;
    const int hsel = lane & 48;  // head*16: shfl source group for my head's ex values

    for (int rr = 0; rr < 4; ++rr) {
        const int r = wave * 4 + rr;
        const int n = row0 + r;
        const int beg = rowptr[n], end = rowptr[n + 1];
        const float sdst = s_dst[n * 4 + head];
        float num0 = 0, num1 = 0, num2 = 0, num3 = 0, den = 0;
        for (int base = beg; base < end; base += 16) {
            const int nn = min(16, end - base);
            int sid = 0;
            float my_ex = 0.0f;
            if (eslot < nn) {
                sid = esrc[base + eslot];
                float v = s_src[sid * 4 + head] + sdst;
                v = v > 0.0f ? v : LEAKY * v;
                my_ex = __expf(v);
            }
            for (int e = 0; e < nn; ++e) {
                float ex = __shfl(my_ex, hsel | e, 64);  // ex of (edge e, my head)
                int s    = __shfl(sid, e, 64);           // src id from lane e
                ushort4 hv = *(const ushort4*)(h_bf + (size_t)s * 256 + c0);
                num0 += ex * bf2f(hv.x);
                num1 += ex * bf2f(hv.y);
                num2 += ex * bf2f(hv.z);
                num3 += ex * bf2f(hv.w);
                den  += ex;
            }
        }
        const float inv = 1.0f / (den > 0.0f ? den : 1.0f);
        ct[r][c0 + 0] = relu_nan(num0 * inv);
        ct[r][c0 + 1] = relu_nan(num1 * inv);
        ct[r][c0 + 2] = relu_nan(num2 * inv);
        ct[r][c0 + 3] = relu_nan(num3 * inv);
    }
    __syncthreads();

    // hidden = relu(concat @ W1 + b1)
    const int r0 = (t >> 6) << 2;
    const int j0 = (t & 63) << 2;
    float acc[4][4];
    {
        float4 bv = *(const float4*)(mb1 + j0);
        for (int q = 0; q < 4; ++q) { acc[q][0] = bv.x; acc[q][1] = bv.y; acc[q][2] = bv.z; acc[q][3] = bv.w; }
    }
    for (int c = 0; c < 256; ++c) {
        float4 wv = *(const float4*)(mW1 + (size_t)c * 256 + j0);
        float x0 = ct[r0 + 0][c], x1 = ct[r0 + 1][c], x2 = ct[r0 + 2][c], x3 = ct[r0 + 3][c];
        acc[0][0] += x0 * wv.x; acc[0][1] += x0 * wv.y; acc[0][2] += x0 * wv.z; acc[0][3] += x0 * wv.w;
        acc[1][0] += x1 * wv.x; acc[1][1] += x1 * wv.y; acc[1][2] += x1 * wv.z; acc[1][3] += x1 * wv.w;
        acc[2][0] += x2 * wv.x; acc[2][1] += x2 * wv.y; acc[2][2] += x2 * wv.z; acc[2][3] += x2 * wv.w;
        acc[3][0] += x3 * wv.x; acc[3][1] += x3 * wv.y; acc[3][2] += x3 * wv.z; acc[3][3] += x3 * wv.w;
    }
    for (int q = 0; q < 4; ++q) {
        float4 o;
        o.x = relu_nan(acc[q][0]); o.y = relu_nan(acc[q][1]);
        o.z = relu_nan(acc[q][2]); o.w = relu_nan(acc[q][3]);
        *(float4*)&ht[r0 + q][j0] = o;
    }
    __syncthreads();

    // out = hidden @ W2 + b2 (no relu), fp32 output
    const int j2 = (t & 63) << 1;
    float a20[4], a21[4];
    {
        float b0 = mb2[j2], b1 = mb2[j2 + 1];
        for (int q = 0; q < 4; ++q) { a20[q] = b0; a21[q] = b1; }
    }
    for (int c = 0; c < 256; ++c) {
        float w0 = mW2[(size_t)c * 128 + j2];
        float w1 = mW2[(size_t)c * 128 + j2 + 1];
        float h0 = ht[r0 + 0][c], h1 = ht[r0 + 1][c], h2 = ht[r0 + 2][c], h3 = ht[r0 + 3][c];
        a20[0] += h0 * w0; a21[0] += h0 * w1;
        a20[1] += h1 * w0; a21[1] += h1 * w1;
        a20[2] += h2 * w0; a21[2] += h2 * w1;
        a20[3] += h3 * w0; a21[3] += h3 * w1;
    }
    for (int q = 0; q < 4; ++q) {
        float2 o; o.x = a20[q]; o.y = a21[q];
        *(float2*)(out + (size_t)(row0 + r0 + q) * 128 + j2) = o;
    }
}

extern "C" void kernel_launch(void* const* d_in, const int* in_sizes, int n_in,
                              void* d_out, int out_size, void* d_ws, size_t ws_size,
                              hipStream_t stream) {
    const float* X    = (const float*)d_in[0];
    const int* src    = (const int*)d_in[1];
    const int* dst    = (const int*)d_in[2];
    const float* Wn   = (const float*)d_in[3];
    const float* Asrc = (const float*)d_in[4];
    const float* Adst = (const float*)d_in[5];
    const float* W1   = (const float*)d_in[6];
    const float* b1   = (const float*)d_in[7];
    const float* W2   = (const float*)d_in[8];
    const float* b2   = (const float*)d_in[9];
    float* out = (float*)d_out;

    const int N = in_sizes[0] / 128;   // 50000
    const int E = in_sizes[1];         // 800000

    // ws layout (16B-aligned offsets), total ~31.0 MB
    size_t off = 0;
    char* w = (char*)d_ws;
    unsigned short* h_bf = (unsigned short*)(w + off); off += (size_t)N * 256 * 2;   // 25.6 MB
    float* s_src = (float*)(w + off);                  off += (size_t)N * 4 * 4;
    float* s_dst = (float*)(w + off);                  off += (size_t)N * 4 * 4;
    int* cnt     = (int*)(w + off);                    off += (size_t)N * 4;
    int* rowptr  = (int*)(w + off);                    off += ((size_t)(N + 1) * 4 + 15) & ~15ull;
    int* wcnt    = (int*)(w + off);                    off += (size_t)N * 4;
    int* esrc    = (int*)(w + off);                    off += (size_t)E * 4;         // 3.2 MB
    const size_t required = off;

    if (ws_size < required) {
        // Diagnostic: absmax will be ~ws_size in MB.
        k_fill<<<dim3((out_size + 255) / 256), dim3(256), 0, stream>>>(
            out, (float)(ws_size >> 20), out_size);
        return;
    }

    k_zero<<<dim3((N + 255) / 256), dim3(256), 0, stream>>>(cnt, N);
    k_transform<<<dim3(N / 16), dim3(256), 0, stream>>>(X, Wn, Asrc, Adst, h_bf, s_src, s_dst);
    k_hist<<<dim3((E + 255) / 256), dim3(256), 0, stream>>>(dst, cnt, E);
    k_scan<<<dim3(1), dim3(64), 0, stream>>>(cnt, rowptr, wcnt, N, E);
    k_scatter<<<dim3((E + 255) / 256), dim3(256), 0, stream>>>(src, dst, wcnt, esrc, E);
    k_agg_mlp<<<dim3(N / 16), dim3(256), 0, stream>>>(s_src, s_dst, h_bf, rowptr, esrc,
                                                      W1, b1, W2, b2, out);
}

// Round 6
// 530.826 us; speedup vs baseline: 1.6722x; 1.6722x over previous
//
#include <hip/hip_runtime.h>

#define LEAKY 0.2f

__device__ __forceinline__ float bf2f(unsigned short u) {
    return __uint_as_float(((unsigned)u) << 16);
}
__device__ __forceinline__ unsigned short f2bf(float f) {
    unsigned u = __float_as_uint(f);
    unsigned r = (u + 0x7fffu + ((u >> 16) & 1u)) >> 16;  // RNE
    return (unsigned short)r;
}
// NaN-propagating relu
__device__ __forceinline__ float relu_nan(float v) { return v < 0.0f ? 0.0f : v; }

// ---------- K_fill: fp32-fill output (ws-too-small diagnosis) ----------
__global__ void k_fill(float* __restrict__ p, float val, int n) {
    int i = blockIdx.x * blockDim.x + threadIdx.x;
    if (i < n) p[i] = val;
}

// ---------- K_zero ----------
__global__ void k_zero(int* __restrict__ cnt, int n) {
    int i = blockIdx.x * blockDim.x + threadIdx.x;
    if (i < n) cnt[i] = 0;
}

// ---------- K1: h = X @ W_n (per-head, fp32) + node scores s_src/s_dst ----------
__global__ __launch_bounds__(256) void k_transform(
    const float* __restrict__ X, const float* __restrict__ Wn,
    const float* __restrict__ Asrc, const float* __restrict__ Adst,
    unsigned short* __restrict__ h_out, float* __restrict__ s_src, float* __restrict__ s_dst) {
    __shared__ float xt[16][132];
    const int t = threadIdx.x;
    const int row0 = blockIdx.x * 16;

    for (int i = t; i < 16 * 32; i += 256) {   // 16 rows x 32 float4
        int r = i >> 5, cp = i & 31;
        float4 v = ((const float4*)(X + (size_t)(row0 + r) * 128))[cp];
        xt[r][cp * 4 + 0] = v.x; xt[r][cp * 4 + 1] = v.y;
        xt[r][cp * 4 + 2] = v.z; xt[r][cp * 4 + 3] = v.w;
    }
    __syncthreads();

    const int r0 = (t >> 6) << 2;
    const int j0 = (t & 63) << 2;
    const int head = j0 >> 6;
    const int dd = j0 & 63;
    const float* wbase = Wn + (size_t)head * 128 * 64 + dd;

    float acc[4][4] = {};
    for (int c = 0; c < 128; ++c) {
        float4 wv = *(const float4*)(wbase + (size_t)c * 64);
        float x0 = xt[r0 + 0][c], x1 = xt[r0 + 1][c], x2 = xt[r0 + 2][c], x3 = xt[r0 + 3][c];
        acc[0][0] += x0 * wv.x; acc[0][1] += x0 * wv.y; acc[0][2] += x0 * wv.z; acc[0][3] += x0 * wv.w;
        acc[1][0] += x1 * wv.x; acc[1][1] += x1 * wv.y; acc[1][2] += x1 * wv.z; acc[1][3] += x1 * wv.w;
        acc[2][0] += x2 * wv.x; acc[2][1] += x2 * wv.y; acc[2][2] += x2 * wv.z; acc[2][3] += x2 * wv.w;
        acc[3][0] += x3 * wv.x; acc[3][1] += x3 * wv.y; acc[3][2] += x3 * wv.z; acc[3][3] += x3 * wv.w;
    }

    for (int rr = 0; rr < 4; ++rr) {
        ushort4 o;
        o.x = f2bf(acc[rr][0]); o.y = f2bf(acc[rr][1]);
        o.z = f2bf(acc[rr][2]); o.w = f2bf(acc[rr][3]);
        *(ushort4*)(h_out + (size_t)(row0 + r0 + rr) * 256 + j0) = o;
    }

    float4 as4 = *(const float4*)(Asrc + head * 64 + dd);
    float4 ad4 = *(const float4*)(Adst + head * 64 + dd);
    for (int rr = 0; rr < 4; ++rr) {
        float ps = acc[rr][0] * as4.x + acc[rr][1] * as4.y + acc[rr][2] * as4.z + acc[rr][3] * as4.w;
        float pd = acc[rr][0] * ad4.x + acc[rr][1] * ad4.y + acc[rr][2] * ad4.z + acc[rr][3] * ad4.w;
        for (int m = 1; m < 16; m <<= 1) {
            ps += __shfl_xor(ps, m, 64);
            pd += __shfl_xor(pd, m, 64);
        }
        if ((t & 15) == 0) {
            s_src[(row0 + r0 + rr) * 4 + head] = ps;
            s_dst[(row0 + r0 + rr) * 4 + head] = pd;
        }
    }
}

// ---------- K2: histogram of dst degrees ----------
__global__ void k_hist(const int* __restrict__ dst, int* __restrict__ cnt, int E) {
    int e = blockIdx.x * blockDim.x + threadIdx.x;
    if (e < E) atomicAdd(cnt + dst[e], 1);
}

// ---------- K3a: block-local exclusive scan (256 elems/block) + block totals ----------
__global__ __launch_bounds__(256) void k_scan1(
    const int* __restrict__ cnt, int* __restrict__ rowptr, int* __restrict__ bsum, int N) {
    __shared__ int wtot[4];
    const int lane = threadIdx.x & 63, wave = threadIdx.x >> 6;
    const int i = blockIdx.x * 256 + threadIdx.x;
    int v = (i < N) ? cnt[i] : 0;
    int x = v;
    for (int off = 1; off < 64; off <<= 1) {
        int y = __shfl_up(x, off, 64);
        if (lane >= off) x += y;
    }
    if (lane == 63) wtot[wave] = x;
    __syncthreads();
    int wo = 0;
    for (int wv = 0; wv < wave; ++wv) wo += wtot[wv];
    if (i < N) rowptr[i] = wo + x - v;            // block-local exclusive
    if (threadIdx.x == 255) bsum[blockIdx.x] = wo + x;  // block total
}

// ---------- K3b: exclusive scan of block sums (single wave; nb ~196 -> 4 iters) ----------
__global__ void k_scan2(int* __restrict__ bsum, int nb) {
    const int lane = threadIdx.x;  // 64 threads, 1 block
    int carry = 0;
    for (int base = 0; base < nb; base += 64) {
        int i = base + lane;
        int v = (i < nb) ? bsum[i] : 0;
        int x = v;
        for (int off = 1; off < 64; off <<= 1) {
            int y = __shfl_up(x, off, 64);
            if (lane >= off) x += y;
        }
        if (i < nb) bsum[i] = carry + x - v;
        carry += __shfl(x, 63, 64);
    }
}

// ---------- K3c: add block offsets; produce final rowptr + wcnt ----------
__global__ void k_scan3(int* __restrict__ rowptr, const int* __restrict__ bsum,
                        int* __restrict__ wcnt, int N, int E) {
    int i = blockIdx.x * blockDim.x + threadIdx.x;
    if (i < N) {
        int v = rowptr[i] + bsum[i >> 8];
        rowptr[i] = v;
        wcnt[i] = v;
    }
    if (i == N) rowptr[N] = E;
}

// ---------- K4: scatter src ids into CSR order ----------
__global__ void k_scatter(const int* __restrict__ src, const int* __restrict__ dst,
                          int* __restrict__ wcnt, int* __restrict__ esrc, int E) {
    int e = blockIdx.x * blockDim.x + threadIdx.x;
    if (e < E) {
        int pos = atomicAdd(wcnt + dst[e], 1);
        esrc[pos] = src[e];
    }
}

// ---------- K5: per-dst gather-aggregate (registers only) + fused 2-layer MLP ----------
__global__ __launch_bounds__(256) void k_agg_mlp(
    const float* __restrict__ s_src, const float* __restrict__ s_dst,
    const unsigned short* __restrict__ h_bf,
    const int* __restrict__ rowptr, const int* __restrict__ esrc,
    const float* __restrict__ mW1, const float* __restrict__ mb1,
    const float* __restrict__ mW2, const float* __restrict__ mb2,
    float* __restrict__ out) {
    __shared__ float ct[16][260];
    __shared__ float ht[16][260];
    const int t = threadIdx.x;
    const int lane = t & 63;
    const int wave = t >> 6;
    const int row0 = blockIdx.x * 16;
    const int head = lane >> 4;
    const int c0 = lane << 2;
    const int eslot = lane & 15;
    const int hsel = lane & 48;  // head*16: shfl source group for my head's ex values

    for (int rr = 0; rr < 4; ++rr) {
        const int r = wave * 4 + rr;
        const int n = row0 + r;
        const int beg = rowptr[n], end = rowptr[n + 1];
        const float sdst = s_dst[n * 4 + head];
        float num0 = 0, num1 = 0, num2 = 0, num3 = 0, den = 0;
        for (int base = beg; base < end; base += 16) {
            const int nn = min(16, end - base);
            int sid = 0;
            float my_ex = 0.0f;
            if (eslot < nn) {
                sid = esrc[base + eslot];
                float v = s_src[sid * 4 + head] + sdst;
                v = v > 0.0f ? v : LEAKY * v;
                my_ex = __expf(v);
            }
            for (int e = 0; e < nn; ++e) {
                float ex = __shfl(my_ex, hsel | e, 64);
                int s    = __shfl(sid, e, 64);
                ushort4 hv = *(const ushort4*)(h_bf + (size_t)s * 256 + c0);
                num0 += ex * bf2f(hv.x);
                num1 += ex * bf2f(hv.y);
                num2 += ex * bf2f(hv.z);
                num3 += ex * bf2f(hv.w);
                den  += ex;
            }
        }
        const float inv = 1.0f / (den > 0.0f ? den : 1.0f);
        ct[r][c0 + 0] = relu_nan(num0 * inv);
        ct[r][c0 + 1] = relu_nan(num1 * inv);
        ct[r][c0 + 2] = relu_nan(num2 * inv);
        ct[r][c0 + 3] = relu_nan(num3 * inv);
    }
    __syncthreads();

    // hidden = relu(concat @ W1 + b1)
    const int r0 = (t >> 6) << 2;
    const int j0 = (t & 63) << 2;
    float acc[4][4];
    {
        float4 bv = *(const float4*)(mb1 + j0);
        for (int q = 0; q < 4; ++q) { acc[q][0] = bv.x; acc[q][1] = bv.y; acc[q][2] = bv.z; acc[q][3] = bv.w; }
    }
    for (int c = 0; c < 256; ++c) {
        float4 wv = *(const float4*)(mW1 + (size_t)c * 256 + j0);
        float x0 = ct[r0 + 0][c], x1 = ct[r0 + 1][c], x2 = ct[r0 + 2][c], x3 = ct[r0 + 3][c];
        acc[0][0] += x0 * wv.x; acc[0][1] += x0 * wv.y; acc[0][2] += x0 * wv.z; acc[0][3] += x0 * wv.w;
        acc[1][0] += x1 * wv.x; acc[1][1] += x1 * wv.y; acc[1][2] += x1 * wv.z; acc[1][3] += x1 * wv.w;
        acc[2][0] += x2 * wv.x; acc[2][1] += x2 * wv.y; acc[2][2] += x2 * wv.z; acc[2][3] += x2 * wv.w;
        acc[3][0] += x3 * wv.x; acc[3][1] += x3 * wv.y; acc[3][2] += x3 * wv.z; acc[3][3] += x3 * wv.w;
    }
    for (int q = 0; q < 4; ++q) {
        float4 o;
        o.x = relu_nan(acc[q][0]); o.y = relu_nan(acc[q][1]);
        o.z = relu_nan(acc[q][2]); o.w = relu_nan(acc[q][3]);
        *(float4*)&ht[r0 + q][j0] = o;
    }
    __syncthreads();

    // out = hidden @ W2 + b2 (fp32 output)
    const int j2 = (t & 63) << 1;
    float a20[4], a21[4];
    {
        float b0 = mb2[j2], b1 = mb2[j2 + 1];
        for (int q = 0; q < 4; ++q) { a20[q] = b0; a21[q] = b1; }
    }
    for (int c = 0; c < 256; ++c) {
        float w0 = mW2[(size_t)c * 128 + j2];
        float w1 = mW2[(size_t)c * 128 + j2 + 1];
        float h0 = ht[r0 + 0][c], h1 = ht[r0 + 1][c], h2 = ht[r0 + 2][c], h3 = ht[r0 + 3][c];
        a20[0] += h0 * w0; a21[0] += h0 * w1;
        a20[1] += h1 * w0; a21[1] += h1 * w1;
        a20[2] += h2 * w0; a21[2] += h2 * w1;
        a20[3] += h3 * w0; a21[3] += h3 * w1;
    }
    for (int q = 0; q < 4; ++q) {
        float2 o; o.x = a20[q]; o.y = a21[q];
        *(float2*)(out + (size_t)(row0 + r0 + q) * 128 + j2) = o;
    }
}

extern "C" void kernel_launch(void* const* d_in, const int* in_sizes, int n_in,
                              void* d_out, int out_size, void* d_ws, size_t ws_size,
                              hipStream_t stream) {
    const float* X    = (const float*)d_in[0];
    const int* src    = (const int*)d_in[1];
    const int* dst    = (const int*)d_in[2];
    const float* Wn   = (const float*)d_in[3];
    const float* Asrc = (const float*)d_in[4];
    const float* Adst = (const float*)d_in[5];
    const float* W1   = (const float*)d_in[6];
    const float* b1   = (const float*)d_in[7];
    const float* W2   = (const float*)d_in[8];
    const float* b2   = (const float*)d_in[9];
    float* out = (float*)d_out;

    const int N = in_sizes[0] / 128;   // 50000
    const int E = in_sizes[1];         // 800000
    const int NB = (N + 255) / 256;    // scan blocks

    // ws layout (16B-aligned offsets), total ~31 MB
    size_t off = 0;
    char* w = (char*)d_ws;
    unsigned short* h_bf = (unsigned short*)(w + off); off += (size_t)N * 256 * 2;   // 25.6 MB
    float* s_src = (float*)(w + off);                  off += (size_t)N * 4 * 4;
    float* s_dst = (float*)(w + off);                  off += (size_t)N * 4 * 4;
    int* cnt     = (int*)(w + off);                    off += (size_t)N * 4;
    int* rowptr  = (int*)(w + off);                    off += ((size_t)(N + 1) * 4 + 15) & ~15ull;
    int* wcnt    = (int*)(w + off);                    off += (size_t)N * 4;
    int* bsum    = (int*)(w + off);                    off += ((size_t)NB * 4 + 15) & ~15ull;
    int* esrc    = (int*)(w + off);                    off += (size_t)E * 4;         // 3.2 MB
    const size_t required = off;

    if (ws_size < required) {
        k_fill<<<dim3((out_size + 255) / 256), dim3(256), 0, stream>>>(
            out, (float)(ws_size >> 20), out_size);
        return;
    }

    k_zero<<<dim3((N + 255) / 256), dim3(256), 0, stream>>>(cnt, N);
    k_transform<<<dim3(N / 16), dim3(256), 0, stream>>>(X, Wn, Asrc, Adst, h_bf, s_src, s_dst);
    k_hist<<<dim3((E + 255) / 256), dim3(256), 0, stream>>>(dst, cnt, E);
    k_scan1<<<dim3(NB), dim3(256), 0, stream>>>(cnt, rowptr, bsum, N);
    k_scan2<<<dim3(1), dim3(64), 0, stream>>>(bsum, NB);
    k_scan3<<<dim3((N + 256) / 256), dim3(256), 0, stream>>>(rowptr, bsum, wcnt, N, E);
    k_scatter<<<dim3((E + 255) / 256), dim3(256), 0, stream>>>(src, dst, wcnt, esrc, E);
    k_agg_mlp<<<dim3(N / 16), dim3(256), 0, stream>>>(s_src, s_dst, h_bf, rowptr, esrc,
                                                      W1, b1, W2, b2, out);
}

// Round 7
// 485.421 us; speedup vs baseline: 1.8286x; 1.0935x over previous
//
#include <hip/hip_runtime.h>

#define LEAKY 0.2f

__device__ __forceinline__ float bf2f(unsigned short u) {
    return __uint_as_float(((unsigned)u) << 16);
}
__device__ __forceinline__ unsigned short f2bf(float f) {
    unsigned u = __float_as_uint(f);
    unsigned r = (u + 0x7fffu + ((u >> 16) & 1u)) >> 16;  // RNE
    return (unsigned short)r;
}
// NaN-propagating relu
__device__ __forceinline__ float relu_nan(float v) { return v < 0.0f ? 0.0f : v; }

// ---------- K_fill: fp32-fill output (ws-too-small diagnosis) ----------
__global__ void k_fill(float* __restrict__ p, float val, int n) {
    int i = blockIdx.x * blockDim.x + threadIdx.x;
    if (i < n) p[i] = val;
}

// ---------- K_zero ----------
__global__ void k_zero(int* __restrict__ cnt, int n) {
    int i = blockIdx.x * blockDim.x + threadIdx.x;
    if (i < n) cnt[i] = 0;
}

// ---------- K1: h = X @ W_n (per-head, fp32) + node scores s_src/s_dst ----------
__global__ __launch_bounds__(256) void k_transform(
    const float* __restrict__ X, const float* __restrict__ Wn,
    const float* __restrict__ Asrc, const float* __restrict__ Adst,
    unsigned short* __restrict__ h_out, float* __restrict__ s_src, float* __restrict__ s_dst) {
    __shared__ float xt[16][132];
    const int t = threadIdx.x;
    const int row0 = blockIdx.x * 16;

    for (int i = t; i < 16 * 32; i += 256) {   // 16 rows x 32 float4
        int r = i >> 5, cp = i & 31;
        float4 v = ((const float4*)(X + (size_t)(row0 + r) * 128))[cp];
        xt[r][cp * 4 + 0] = v.x; xt[r][cp * 4 + 1] = v.y;
        xt[r][cp * 4 + 2] = v.z; xt[r][cp * 4 + 3] = v.w;
    }
    __syncthreads();

    const int r0 = (t >> 6) << 2;
    const int j0 = (t & 63) << 2;
    const int head = j0 >> 6;
    const int dd = j0 & 63;
    const float* wbase = Wn + (size_t)head * 128 * 64 + dd;

    float acc[4][4] = {};
    for (int c = 0; c < 128; ++c) {
        float4 wv = *(const float4*)(wbase + (size_t)c * 64);
        float x0 = xt[r0 + 0][c], x1 = xt[r0 + 1][c], x2 = xt[r0 + 2][c], x3 = xt[r0 + 3][c];
        acc[0][0] += x0 * wv.x; acc[0][1] += x0 * wv.y; acc[0][2] += x0 * wv.z; acc[0][3] += x0 * wv.w;
        acc[1][0] += x1 * wv.x; acc[1][1] += x1 * wv.y; acc[1][2] += x1 * wv.z; acc[1][3] += x1 * wv.w;
        acc[2][0] += x2 * wv.x; acc[2][1] += x2 * wv.y; acc[2][2] += x2 * wv.z; acc[2][3] += x2 * wv.w;
        acc[3][0] += x3 * wv.x; acc[3][1] += x3 * wv.y; acc[3][2] += x3 * wv.z; acc[3][3] += x3 * wv.w;
    }

    for (int rr = 0; rr < 4; ++rr) {
        ushort4 o;
        o.x = f2bf(acc[rr][0]); o.y = f2bf(acc[rr][1]);
        o.z = f2bf(acc[rr][2]); o.w = f2bf(acc[rr][3]);
        *(ushort4*)(h_out + (size_t)(row0 + r0 + rr) * 256 + j0) = o;
    }

    float4 as4 = *(const float4*)(Asrc + head * 64 + dd);
    float4 ad4 = *(const float4*)(Adst + head * 64 + dd);
    for (int rr = 0; rr < 4; ++rr) {
        float ps = acc[rr][0] * as4.x + acc[rr][1] * as4.y + acc[rr][2] * as4.z + acc[rr][3] * as4.w;
        float pd = acc[rr][0] * ad4.x + acc[rr][1] * ad4.y + acc[rr][2] * ad4.z + acc[rr][3] * ad4.w;
        for (int m = 1; m < 16; m <<= 1) {
            ps += __shfl_xor(ps, m, 64);
            pd += __shfl_xor(pd, m, 64);
        }
        if ((t & 15) == 0) {
            s_src[(row0 + r0 + rr) * 4 + head] = ps;
            s_dst[(row0 + r0 + rr) * 4 + head] = pd;
        }
    }
}

// ---------- K2: histogram of dst degrees ----------
__global__ void k_hist(const int* __restrict__ dst, int* __restrict__ cnt, int E) {
    int e = blockIdx.x * blockDim.x + threadIdx.x;
    if (e < E) atomicAdd(cnt + dst[e], 1);
}

// ---------- K3a: block-local exclusive scan (256 elems/block) + block totals ----------
__global__ __launch_bounds__(256) void k_scan1(
    const int* __restrict__ cnt, int* __restrict__ rowptr, int* __restrict__ bsum, int N) {
    __shared__ int wtot[4];
    const int lane = threadIdx.x & 63, wave = threadIdx.x >> 6;
    const int i = blockIdx.x * 256 + threadIdx.x;
    int v = (i < N) ? cnt[i] : 0;
    int x = v;
    for (int off = 1; off < 64; off <<= 1) {
        int y = __shfl_up(x, off, 64);
        if (lane >= off) x += y;
    }
    if (lane == 63) wtot[wave] = x;
    __syncthreads();
    int wo = 0;
    for (int wv = 0; wv < wave; ++wv) wo += wtot[wv];
    if (i < N) rowptr[i] = wo + x - v;
    if (threadIdx.x == 255) bsum[blockIdx.x] = wo + x;
}

// ---------- K3b: exclusive scan of block sums ----------
__global__ void k_scan2(int* __restrict__ bsum, int nb) {
    const int lane = threadIdx.x;
    int carry = 0;
    for (int base = 0; base < nb; base += 64) {
        int i = base + lane;
        int v = (i < nb) ? bsum[i] : 0;
        int x = v;
        for (int off = 1; off < 64; off <<= 1) {
            int y = __shfl_up(x, off, 64);
            if (lane >= off) x += y;
        }
        if (i < nb) bsum[i] = carry + x - v;
        carry += __shfl(x, 63, 64);
    }
}

// ---------- K3c: add block offsets ----------
__global__ void k_scan3(int* __restrict__ rowptr, const int* __restrict__ bsum,
                        int* __restrict__ wcnt, int N, int E) {
    int i = blockIdx.x * blockDim.x + threadIdx.x;
    if (i < N) {
        int v = rowptr[i] + bsum[i >> 8];
        rowptr[i] = v;
        wcnt[i] = v;
    }
    if (i == N) rowptr[N] = E;
}

// ---------- K4: scatter src ids into CSR order ----------
__global__ void k_scatter(const int* __restrict__ src, const int* __restrict__ dst,
                          int* __restrict__ wcnt, int* __restrict__ esrc, int E) {
    int e = blockIdx.x * blockDim.x + threadIdx.x;
    if (e < E) {
        int pos = atomicAdd(wcnt + dst[e], 1);
        esrc[pos] = src[e];
    }
}

// ---------- K5: per-dst gather-aggregate + fused 2-layer MLP ----------
// Edge chunks processed with a FIXED 16-iter unrolled loop (invalid slots masked
// by ex=0, sid=0 -> loads hit the hot h[0] line): 16 independent 8B loads in
// flight per wave instead of one serialized load per iteration.
__global__ __launch_bounds__(256) void k_agg_mlp(
    const float* __restrict__ s_src, const float* __restrict__ s_dst,
    const unsigned short* __restrict__ h_bf,
    const int* __restrict__ rowptr, const int* __restrict__ esrc,
    const float* __restrict__ mW1, const float* __restrict__ mb1,
    const float* __restrict__ mW2, const float* __restrict__ mb2,
    float* __restrict__ out) {
    __shared__ float ct[16][260];
    __shared__ float ht[16][260];
    const int t = threadIdx.x;
    const int lane = t & 63;
    const int wave = t >> 6;
    const int row0 = blockIdx.x * 16;
    const int head = lane >> 4;
    const int c0 = lane << 2;
    const int eslot = lane & 15;
    const int hsel = lane & 48;

    for (int rr = 0; rr < 4; ++rr) {
        const int r = wave * 4 + rr;
        const int n = row0 + r;
        const int beg = rowptr[n], end = rowptr[n + 1];
        const float sdst = s_dst[n * 4 + head];
        float num0 = 0, num1 = 0, num2 = 0, num3 = 0, den = 0;
        for (int base = beg; base < end; base += 16) {
            const int nn = end - base;   // > 0
            int sid = 0;
            float my_ex = 0.0f;
            if (eslot < nn) {
                sid = esrc[base + eslot];
                float v = s_src[sid * 4 + head] + sdst;
                v = v > 0.0f ? v : LEAKY * v;
                my_ex = __expf(v);
            }
#pragma unroll
            for (int e = 0; e < 16; ++e) {
                float ex = __shfl(my_ex, hsel | e, 64);  // 0 for padded slots
                int s    = __shfl(sid, e, 64);           // 0 for padded slots
                ushort4 hv = *(const ushort4*)(h_bf + (size_t)s * 256 + c0);
                num0 += ex * bf2f(hv.x);
                num1 += ex * bf2f(hv.y);
                num2 += ex * bf2f(hv.z);
                num3 += ex * bf2f(hv.w);
                den  += ex;
            }
        }
        const float inv = 1.0f / (den > 0.0f ? den : 1.0f);
        ct[r][c0 + 0] = relu_nan(num0 * inv);
        ct[r][c0 + 1] = relu_nan(num1 * inv);
        ct[r][c0 + 2] = relu_nan(num2 * inv);
        ct[r][c0 + 3] = relu_nan(num3 * inv);
    }
    __syncthreads();

    // hidden = relu(concat @ W1 + b1)
    const int r0 = (t >> 6) << 2;
    const int j0 = (t & 63) << 2;
    float acc[4][4];
    {
        float4 bv = *(const float4*)(mb1 + j0);
        for (int q = 0; q < 4; ++q) { acc[q][0] = bv.x; acc[q][1] = bv.y; acc[q][2] = bv.z; acc[q][3] = bv.w; }
    }
    for (int c = 0; c < 256; ++c) {
        float4 wv = *(const float4*)(mW1 + (size_t)c * 256 + j0);
        float x0 = ct[r0 + 0][c], x1 = ct[r0 + 1][c], x2 = ct[r0 + 2][c], x3 = ct[r0 + 3][c];
        acc[0][0] += x0 * wv.x; acc[0][1] += x0 * wv.y; acc[0][2] += x0 * wv.z; acc[0][3] += x0 * wv.w;
        acc[1][0] += x1 * wv.x; acc[1][1] += x1 * wv.y; acc[1][2] += x1 * wv.z; acc[1][3] += x1 * wv.w;
        acc[2][0] += x2 * wv.x; acc[2][1] += x2 * wv.y; acc[2][2] += x2 * wv.z; acc[2][3] += x2 * wv.w;
        acc[3][0] += x3 * wv.x; acc[3][1] += x3 * wv.y; acc[3][2] += x3 * wv.z; acc[3][3] += x3 * wv.w;
    }
    for (int q = 0; q < 4; ++q) {
        float4 o;
        o.x = relu_nan(acc[q][0]); o.y = relu_nan(acc[q][1]);
        o.z = relu_nan(acc[q][2]); o.w = relu_nan(acc[q][3]);
        *(float4*)&ht[r0 + q][j0] = o;
    }
    __syncthreads();

    // out = hidden @ W2 + b2 (fp32 output)
    const int j2 = (t & 63) << 1;
    float a20[4], a21[4];
    {
        float2 bv = *(const float2*)(mb2 + j2);
        for (int q = 0; q < 4; ++q) { a20[q] = bv.x; a21[q] = bv.y; }
    }
    for (int c = 0; c < 256; ++c) {
        float2 wv = *(const float2*)(mW2 + (size_t)c * 128 + j2);
        float h0 = ht[r0 + 0][c], h1 = ht[r0 + 1][c], h2 = ht[r0 + 2][c], h3 = ht[r0 + 3][c];
        a20[0] += h0 * wv.x; a21[0] += h0 * wv.y;
        a20[1] += h1 * wv.x; a21[1] += h1 * wv.y;
        a20[2] += h2 * wv.x; a21[2] += h2 * wv.y;
        a20[3] += h3 * wv.x; a21[3] += h3 * wv.y;
    }
    for (int q = 0; q < 4; ++q) {
        float2 o; o.x = a20[q]; o.y = a21[q];
        *(float2*)(out + (size_t)(row0 + r0 + q) * 128 + j2) = o;
    }
}

extern "C" void kernel_launch(void* const* d_in, const int* in_sizes, int n_in,
                              void* d_out, int out_size, void* d_ws, size_t ws_size,
                              hipStream_t stream) {
    const float* X    = (const float*)d_in[0];
    const int* src    = (const int*)d_in[1];
    const int* dst    = (const int*)d_in[2];
    const float* Wn   = (const float*)d_in[3];
    const float* Asrc = (const float*)d_in[4];
    const float* Adst = (const float*)d_in[5];
    const float* W1   = (const float*)d_in[6];
    const float* b1   = (const float*)d_in[7];
    const float* W2   = (const float*)d_in[8];
    const float* b2   = (const float*)d_in[9];
    float* out = (float*)d_out;

    const int N = in_sizes[0] / 128;   // 50000
    const int E = in_sizes[1];         // 800000
    const int NB = (N + 255) / 256;

    // ws layout (16B-aligned offsets), total ~31 MB
    size_t off = 0;
    char* w = (char*)d_ws;
    unsigned short* h_bf = (unsigned short*)(w + off); off += (size_t)N * 256 * 2;
    float* s_src = (float*)(w + off);                  off += (size_t)N * 4 * 4;
    float* s_dst = (float*)(w + off);                  off += (size_t)N * 4 * 4;
    int* cnt     = (int*)(w + off);                    off += (size_t)N * 4;
    int* rowptr  = (int*)(w + off);                    off += ((size_t)(N + 1) * 4 + 15) & ~15ull;
    int* wcnt    = (int*)(w + off);                    off += (size_t)N * 4;
    int* bsum    = (int*)(w + off);                    off += ((size_t)NB * 4 + 15) & ~15ull;
    int* esrc    = (int*)(w + off);                    off += (size_t)E * 4;
    const size_t required = off;

    if (ws_size < required) {
        k_fill<<<dim3((out_size + 255) / 256), dim3(256), 0, stream>>>(
            out, (float)(ws_size >> 20), out_size);
        return;
    }

    k_zero<<<dim3((N + 255) / 256), dim3(256), 0, stream>>>(cnt, N);
    k_transform<<<dim3(N / 16), dim3(256), 0, stream>>>(X, Wn, Asrc, Adst, h_bf, s_src, s_dst);
    k_hist<<<dim3((E + 255) / 256), dim3(256), 0, stream>>>(dst, cnt, E);
    k_scan1<<<dim3(NB), dim3(256), 0, stream>>>(cnt, rowptr, bsum, N);
    k_scan2<<<dim3(1), dim3(64), 0, stream>>>(bsum, NB);
    k_scan3<<<dim3((N + 256) / 256), dim3(256), 0, stream>>>(rowptr, bsum, wcnt, N, E);
    k_scatter<<<dim3((E + 255) / 256), dim3(256), 0, stream>>>(src, dst, wcnt, esrc, E);
    k_agg_mlp<<<dim3(N / 16), dim3(256), 0, stream>>>(s_src, s_dst, h_bf, rowptr, esrc,
                                                      W1, b1, W2, b2, out);
}

// Round 8
// 406.911 us; speedup vs baseline: 2.1814x; 1.1929x over previous
//
#include <hip/hip_runtime.h>

#define LEAKY 0.2f

typedef __attribute__((ext_vector_type(8))) short short8;   // 8 bf16 = 4 VGPR (MFMA A/B frag)
typedef __attribute__((ext_vector_type(4))) float floatx4;  // MFMA C/D frag

__device__ __forceinline__ float bf2f(unsigned short u) {
    return __uint_as_float(((unsigned)u) << 16);
}
__device__ __forceinline__ unsigned short f2bf(float f) {
    unsigned u = __float_as_uint(f);
    unsigned r = (u + 0x7fffu + ((u >> 16) & 1u)) >> 16;  // RNE
    return (unsigned short)r;
}
__device__ __forceinline__ float relu_nan(float v) { return v < 0.0f ? 0.0f : v; }

// ---------- K_fill: fp32-fill output (ws-too-small diagnosis) ----------
__global__ void k_fill(float* __restrict__ p, float val, int n) {
    int i = blockIdx.x * blockDim.x + threadIdx.x;
    if (i < n) p[i] = val;
}

// ---------- K_zero ----------
__global__ void k_zero(int* __restrict__ cnt, int n) {
    int i = blockIdx.x * blockDim.x + threadIdx.x;
    if (i < n) cnt[i] = 0;
}

// ---------- K_convert: WT[n][k] = bf16(W[k][n])  (transpose + fp32->bf16) ----------
// grid = C blocks (n), block = R threads (k); W is [R][C] row-major.
__global__ void k_convert(const float* __restrict__ W, unsigned short* __restrict__ WT, int R, int C) {
    int k = threadIdx.x, n = blockIdx.x;
    WT[(size_t)n * R + k] = f2bf(W[(size_t)k * C + n]);
}

// ---------- K1: h = X @ W_n (per-head, fp32) + node scores s_src/s_dst ----------
__global__ __launch_bounds__(256) void k_transform(
    const float* __restrict__ X, const float* __restrict__ Wn,
    const float* __restrict__ Asrc, const float* __restrict__ Adst,
    unsigned short* __restrict__ h_out, float* __restrict__ s_src, float* __restrict__ s_dst) {
    __shared__ float xt[16][132];
    const int t = threadIdx.x;
    const int row0 = blockIdx.x * 16;

    for (int i = t; i < 16 * 32; i += 256) {
        int r = i >> 5, cp = i & 31;
        float4 v = ((const float4*)(X + (size_t)(row0 + r) * 128))[cp];
        xt[r][cp * 4 + 0] = v.x; xt[r][cp * 4 + 1] = v.y;
        xt[r][cp * 4 + 2] = v.z; xt[r][cp * 4 + 3] = v.w;
    }
    __syncthreads();

    const int r0 = (t >> 6) << 2;
    const int j0 = (t & 63) << 2;
    const int head = j0 >> 6;
    const int dd = j0 & 63;
    const float* wbase = Wn + (size_t)head * 128 * 64 + dd;

    float acc[4][4] = {};
    for (int c = 0; c < 128; ++c) {
        float4 wv = *(const float4*)(wbase + (size_t)c * 64);
        float x0 = xt[r0 + 0][c], x1 = xt[r0 + 1][c], x2 = xt[r0 + 2][c], x3 = xt[r0 + 3][c];
        acc[0][0] += x0 * wv.x; acc[0][1] += x0 * wv.y; acc[0][2] += x0 * wv.z; acc[0][3] += x0 * wv.w;
        acc[1][0] += x1 * wv.x; acc[1][1] += x1 * wv.y; acc[1][2] += x1 * wv.z; acc[1][3] += x1 * wv.w;
        acc[2][0] += x2 * wv.x; acc[2][1] += x2 * wv.y; acc[2][2] += x2 * wv.z; acc[2][3] += x2 * wv.w;
        acc[3][0] += x3 * wv.x; acc[3][1] += x3 * wv.y; acc[3][2] += x3 * wv.z; acc[3][3] += x3 * wv.w;
    }

    for (int rr = 0; rr < 4; ++rr) {
        ushort4 o;
        o.x = f2bf(acc[rr][0]); o.y = f2bf(acc[rr][1]);
        o.z = f2bf(acc[rr][2]); o.w = f2bf(acc[rr][3]);
        *(ushort4*)(h_out + (size_t)(row0 + r0 + rr) * 256 + j0) = o;
    }

    float4 as4 = *(const float4*)(Asrc + head * 64 + dd);
    float4 ad4 = *(const float4*)(Adst + head * 64 + dd);
    for (int rr = 0; rr < 4; ++rr) {
        float ps = acc[rr][0] * as4.x + acc[rr][1] * as4.y + acc[rr][2] * as4.z + acc[rr][3] * as4.w;
        float pd = acc[rr][0] * ad4.x + acc[rr][1] * ad4.y + acc[rr][2] * ad4.z + acc[rr][3] * ad4.w;
        for (int m = 1; m < 16; m <<= 1) {
            ps += __shfl_xor(ps, m, 64);
            pd += __shfl_xor(pd, m, 64);
        }
        if ((t & 15) == 0) {
            s_src[(row0 + r0 + rr) * 4 + head] = ps;
            s_dst[(row0 + r0 + rr) * 4 + head] = pd;
        }
    }
}

// ---------- K2: histogram of dst degrees ----------
__global__ void k_hist(const int* __restrict__ dst, int* __restrict__ cnt, int E) {
    int e = blockIdx.x * blockDim.x + threadIdx.x;
    if (e < E) atomicAdd(cnt + dst[e], 1);
}

// ---------- K3a/b/c: two-level exclusive scan ----------
__global__ __launch_bounds__(256) void k_scan1(
    const int* __restrict__ cnt, int* __restrict__ rowptr, int* __restrict__ bsum, int N) {
    __shared__ int wtot[4];
    const int lane = threadIdx.x & 63, wave = threadIdx.x >> 6;
    const int i = blockIdx.x * 256 + threadIdx.x;
    int v = (i < N) ? cnt[i] : 0;
    int x = v;
    for (int off = 1; off < 64; off <<= 1) {
        int y = __shfl_up(x, off, 64);
        if (lane >= off) x += y;
    }
    if (lane == 63) wtot[wave] = x;
    __syncthreads();
    int wo = 0;
    for (int wv = 0; wv < wave; ++wv) wo += wtot[wv];
    if (i < N) rowptr[i] = wo + x - v;
    if (threadIdx.x == 255) bsum[blockIdx.x] = wo + x;
}
__global__ void k_scan2(int* __restrict__ bsum, int nb) {
    const int lane = threadIdx.x;
    int carry = 0;
    for (int base = 0; base < nb; base += 64) {
        int i = base + lane;
        int v = (i < nb) ? bsum[i] : 0;
        int x = v;
        for (int off = 1; off < 64; off <<= 1) {
            int y = __shfl_up(x, off, 64);
            if (lane >= off) x += y;
        }
        if (i < nb) bsum[i] = carry + x - v;
        carry += __shfl(x, 63, 64);
    }
}
__global__ void k_scan3(int* __restrict__ rowptr, const int* __restrict__ bsum,
                        int* __restrict__ wcnt, int N, int E) {
    int i = blockIdx.x * blockDim.x + threadIdx.x;
    if (i < N) {
        int v = rowptr[i] + bsum[i >> 8];
        rowptr[i] = v;
        wcnt[i] = v;
    }
    if (i == N) rowptr[N] = E;
}

// ---------- K4: scatter src ids into CSR order ----------
__global__ void k_scatter(const int* __restrict__ src, const int* __restrict__ dst,
                          int* __restrict__ wcnt, int* __restrict__ esrc, int E) {
    int e = blockIdx.x * blockDim.x + threadIdx.x;
    if (e < E) {
        int pos = atomicAdd(wcnt + dst[e], 1);
        esrc[pos] = src[e];
    }
}

// ---------- K5: per-dst gather-aggregate -> concat (bf16, written into d_out) ----------
// ZERO LDS -> 8 waves/SIMD of latency hiding for the random h-gather.
__global__ __launch_bounds__(256) void k_agg(
    const float* __restrict__ s_src, const float* __restrict__ s_dst,
    const unsigned short* __restrict__ h_bf,
    const int* __restrict__ rowptr, const int* __restrict__ esrc,
    unsigned short* __restrict__ concat) {
    const int t = threadIdx.x;
    const int lane = t & 63;
    const int wave = t >> 6;
    const int row0 = blockIdx.x * 16;
    const int head = lane >> 4;
    const int c0 = lane << 2;
    const int eslot = lane & 15;
    const int hsel = lane & 48;

    for (int rr = 0; rr < 4; ++rr) {
        const int n = row0 + wave * 4 + rr;
        const int beg = rowptr[n], end = rowptr[n + 1];
        const float sdst = s_dst[n * 4 + head];
        float num0 = 0, num1 = 0, num2 = 0, num3 = 0, den = 0;
        for (int base = beg; base < end; base += 16) {
            const int nn = end - base;
            int sid = 0;
            float my_ex = 0.0f;
            if (eslot < nn) {
                sid = esrc[base + eslot];
                float v = s_src[sid * 4 + head] + sdst;
                v = v > 0.0f ? v : LEAKY * v;
                my_ex = __expf(v);
            }
#pragma unroll
            for (int e = 0; e < 16; ++e) {
                float ex = __shfl(my_ex, hsel | e, 64);
                int s    = __shfl(sid, e, 64);
                ushort4 hv = *(const ushort4*)(h_bf + (size_t)s * 256 + c0);
                num0 += ex * bf2f(hv.x);
                num1 += ex * bf2f(hv.y);
                num2 += ex * bf2f(hv.z);
                num3 += ex * bf2f(hv.w);
                den  += ex;
            }
        }
        const float inv = 1.0f / (den > 0.0f ? den : 1.0f);
        ushort4 o;
        o.x = f2bf(relu_nan(num0 * inv));
        o.y = f2bf(relu_nan(num1 * inv));
        o.z = f2bf(relu_nan(num2 * inv));
        o.w = f2bf(relu_nan(num3 * inv));
        *(ushort4*)(concat + (size_t)n * 256 + c0) = o;
    }
}

// ---------- K6: MFMA 2-layer MLP.  out = relu(concat@W1+b1)@W2+b2 ----------
// Block = 4 waves, 64 rows (16/wave). Weights pre-transposed bf16: W1T[256][256],
// W2T[128][256] (WT[n][k]). concat is read from d_out (bf16) and overwritten
// with fp32 out by the same block's own rows only -> no race.
// Frag layouts (m89-verified): A[m=lane&15][k=(lane>>4)*8+j], B[n=lane&15][k=(lane>>4)*8+j],
// D: col(n)=lane&15, row(m)=(lane>>4)*4+reg.
__global__ __launch_bounds__(256) void k_mlp_mfma(
    const unsigned short* concat, float* outp,
    const unsigned short* __restrict__ W1T, const float* __restrict__ b1,
    const unsigned short* __restrict__ W2T, const float* __restrict__ b2, int N) {
    __shared__ unsigned short hb[4][16][264];  // per-wave hidden tile (264: pad 8 bf16)
    const int t = threadIdx.x;
    const int lane = t & 63;
    const int wave = t >> 6;
    const int quad = lane >> 4;
    const int lm = lane & 15;
    const int row0 = blockIdx.x * 64 + wave * 16;

    // ---- phase 1: hidden[16][256] = relu(concat @ W1 + b1) ----
    floatx4 acc[16];
#pragma unroll
    for (int j = 0; j < 16; ++j) {
        float b = b1[j * 16 + lm];
        acc[j] = (floatx4){b, b, b, b};
    }
    for (int k0 = 0; k0 < 256; k0 += 32) {
        int ar = row0 + lm; if (ar > N - 1) ar = N - 1;
        short8 a = *(const short8*)(concat + (size_t)ar * 256 + k0 + quad * 8);
#pragma unroll
        for (int j = 0; j < 16; ++j) {
            short8 b = *(const short8*)(W1T + (size_t)(j * 16 + lm) * 256 + k0 + quad * 8);
            acc[j] = __builtin_amdgcn_mfma_f32_16x16x32_bf16(a, b, acc[j], 0, 0, 0);
        }
    }
#pragma unroll
    for (int j = 0; j < 16; ++j) {
#pragma unroll
        for (int q = 0; q < 4; ++q) {
            hb[wave][quad * 4 + q][j * 16 + lm] = f2bf(relu_nan(acc[j][q]));
        }
    }
    // no barrier: hb[wave] is private to this wave; lgkmcnt ordering is enough.

    // ---- phase 2: out[16][128] = hidden @ W2 + b2 ----
    floatx4 a2[8];
#pragma unroll
    for (int j = 0; j < 8; ++j) {
        float b = b2[j * 16 + lm];
        a2[j] = (floatx4){b, b, b, b};
    }
    for (int k0 = 0; k0 < 256; k0 += 32) {
        short8 a = *(const short8*)(&hb[wave][lm][k0 + quad * 8]);
#pragma unroll
        for (int j = 0; j < 8; ++j) {
            short8 b = *(const short8*)(W2T + (size_t)(j * 16 + lm) * 256 + k0 + quad * 8);
            a2[j] = __builtin_amdgcn_mfma_f32_16x16x32_bf16(a, b, a2[j], 0, 0, 0);
        }
    }
#pragma unroll
    for (int j = 0; j < 8; ++j) {
#pragma unroll
        for (int q = 0; q < 4; ++q) {
            int r = row0 + quad * 4 + q;
            if (r < N) outp[(size_t)r * 128 + j * 16 + lm] = a2[j][q];
        }
    }
}

extern "C" void kernel_launch(void* const* d_in, const int* in_sizes, int n_in,
                              void* d_out, int out_size, void* d_ws, size_t ws_size,
                              hipStream_t stream) {
    const float* X    = (const float*)d_in[0];
    const int* src    = (const int*)d_in[1];
    const int* dst    = (const int*)d_in[2];
    const float* Wn   = (const float*)d_in[3];
    const float* Asrc = (const float*)d_in[4];
    const float* Adst = (const float*)d_in[5];
    const float* W1   = (const float*)d_in[6];
    const float* b1   = (const float*)d_in[7];
    const float* W2   = (const float*)d_in[8];
    const float* b2   = (const float*)d_in[9];
    float* out = (float*)d_out;

    const int N = in_sizes[0] / 128;   // 50000
    const int E = in_sizes[1];         // 800000
    const int NB = (N + 255) / 256;

    // ws layout (16B-aligned offsets), total ~31.2 MB
    size_t off = 0;
    char* w = (char*)d_ws;
    unsigned short* h_bf = (unsigned short*)(w + off); off += (size_t)N * 256 * 2;
    float* s_src = (float*)(w + off);                  off += (size_t)N * 4 * 4;
    float* s_dst = (float*)(w + off);                  off += (size_t)N * 4 * 4;
    int* cnt     = (int*)(w + off);                    off += (size_t)N * 4;
    int* rowptr  = (int*)(w + off);                    off += ((size_t)(N + 1) * 4 + 15) & ~15ull;
    int* wcnt    = (int*)(w + off);                    off += (size_t)N * 4;
    int* bsum    = (int*)(w + off);                    off += ((size_t)NB * 4 + 15) & ~15ull;
    int* esrc    = (int*)(w + off);                    off += (size_t)E * 4;
    unsigned short* W1T = (unsigned short*)(w + off);  off += 256 * 256 * 2;
    unsigned short* W2T = (unsigned short*)(w + off);  off += 128 * 256 * 2;
    const size_t required = off;

    if (ws_size < required) {
        k_fill<<<dim3((out_size + 255) / 256), dim3(256), 0, stream>>>(
            out, (float)(ws_size >> 20), out_size);
        return;
    }

    k_zero<<<dim3((N + 255) / 256), dim3(256), 0, stream>>>(cnt, N);
    k_transform<<<dim3(N / 16), dim3(256), 0, stream>>>(X, Wn, Asrc, Adst, h_bf, s_src, s_dst);
    k_hist<<<dim3((E + 255) / 256), dim3(256), 0, stream>>>(dst, cnt, E);
    k_scan1<<<dim3(NB), dim3(256), 0, stream>>>(cnt, rowptr, bsum, N);
    k_scan2<<<dim3(1), dim3(64), 0, stream>>>(bsum, NB);
    k_scan3<<<dim3((N + 256) / 256), dim3(256), 0, stream>>>(rowptr, bsum, wcnt, N, E);
    k_scatter<<<dim3((E + 255) / 256), dim3(256), 0, stream>>>(src, dst, wcnt, esrc, E);
    k_convert<<<dim3(256), dim3(256), 0, stream>>>(W1, W1T, 256, 256);
    k_convert<<<dim3(128), dim3(256), 0, stream>>>(W2, W2T, 256, 128);
    // concat (bf16) is staged inside d_out; k_mlp_mfma reads it and overwrites with fp32.
    k_agg<<<dim3(N / 16), dim3(256), 0, stream>>>(s_src, s_dst, h_bf, rowptr, esrc,
                                                  (unsigned short*)d_out);
    k_mlp_mfma<<<dim3((N + 63) / 64), dim3(256), 0, stream>>>(
        (const unsigned short*)d_out, out, W1T, b1, W2T, b2, N);
}

// Round 9
// 344.094 us; speedup vs baseline: 2.5797x; 1.1826x over previous
//
#include <hip/hip_runtime.h>

#define LEAKY 0.2f

typedef __attribute__((ext_vector_type(8))) short short8;   // 8 bf16 (MFMA A/B frag)
typedef __attribute__((ext_vector_type(4))) float floatx4;  // MFMA C/D frag

__device__ __forceinline__ float bf2f(unsigned short u) {
    return __uint_as_float(((unsigned)u) << 16);
}
__device__ __forceinline__ unsigned short f2bf(float f) {
    unsigned u = __float_as_uint(f);
    unsigned r = (u + 0x7fffu + ((u >> 16) & 1u)) >> 16;  // RNE
    return (unsigned short)r;
}
__device__ __forceinline__ float relu_nan(float v) { return v < 0.0f ? 0.0f : v; }

// async global->LDS, 16 B per lane (dest must be wave-uniform base + lane*16)
__device__ __forceinline__ void gload_lds16(const void* g, void* l) {
    __builtin_amdgcn_global_load_lds((const __attribute__((address_space(1))) void*)g,
                                     (__attribute__((address_space(3))) void*)l, 16, 0, 0);
}

// ---------- K_fill ----------
__global__ void k_fill(float* __restrict__ p, float val, int n) {
    int i = blockIdx.x * blockDim.x + threadIdx.x;
    if (i < n) p[i] = val;
}

// ---------- K_zero ----------
__global__ void k_zero(int* __restrict__ cnt, int n) {
    int i = blockIdx.x * blockDim.x + threadIdx.x;
    if (i < n) cnt[i] = 0;
}

// ---------- K_convert: WT[n][k] = bf16(W[k][n]) ----------
__global__ void k_convert(const float* __restrict__ W, unsigned short* __restrict__ WT, int R, int C) {
    int k = threadIdx.x, n = blockIdx.x;
    WT[(size_t)n * R + k] = f2bf(W[(size_t)k * C + n]);
}

// ---------- K1: h = X @ W_n (per-head, fp32) + node scores ----------
__global__ __launch_bounds__(256) void k_transform(
    const float* __restrict__ X, const float* __restrict__ Wn,
    const float* __restrict__ Asrc, const float* __restrict__ Adst,
    unsigned short* __restrict__ h_out, float* __restrict__ s_src, float* __restrict__ s_dst) {
    __shared__ float xt[16][132];
    const int t = threadIdx.x;
    const int row0 = blockIdx.x * 16;

    for (int i = t; i < 16 * 32; i += 256) {
        int r = i >> 5, cp = i & 31;
        float4 v = ((const float4*)(X + (size_t)(row0 + r) * 128))[cp];
        xt[r][cp * 4 + 0] = v.x; xt[r][cp * 4 + 1] = v.y;
        xt[r][cp * 4 + 2] = v.z; xt[r][cp * 4 + 3] = v.w;
    }
    __syncthreads();

    const int r0 = (t >> 6) << 2;
    const int j0 = (t & 63) << 2;
    const int head = j0 >> 6;
    const int dd = j0 & 63;
    const float* wbase = Wn + (size_t)head * 128 * 64 + dd;

    float acc[4][4] = {};
    for (int c = 0; c < 128; ++c) {
        float4 wv = *(const float4*)(wbase + (size_t)c * 64);
        float x0 = xt[r0 + 0][c], x1 = xt[r0 + 1][c], x2 = xt[r0 + 2][c], x3 = xt[r0 + 3][c];
        acc[0][0] += x0 * wv.x; acc[0][1] += x0 * wv.y; acc[0][2] += x0 * wv.z; acc[0][3] += x0 * wv.w;
        acc[1][0] += x1 * wv.x; acc[1][1] += x1 * wv.y; acc[1][2] += x1 * wv.z; acc[1][3] += x1 * wv.w;
        acc[2][0] += x2 * wv.x; acc[2][1] += x2 * wv.y; acc[2][2] += x2 * wv.z; acc[2][3] += x2 * wv.w;
        acc[3][0] += x3 * wv.x; acc[3][1] += x3 * wv.y; acc[3][2] += x3 * wv.z; acc[3][3] += x3 * wv.w;
    }

    for (int rr = 0; rr < 4; ++rr) {
        ushort4 o;
        o.x = f2bf(acc[rr][0]); o.y = f2bf(acc[rr][1]);
        o.z = f2bf(acc[rr][2]); o.w = f2bf(acc[rr][3]);
        *(ushort4*)(h_out + (size_t)(row0 + r0 + rr) * 256 + j0) = o;
    }

    float4 as4 = *(const float4*)(Asrc + head * 64 + dd);
    float4 ad4 = *(const float4*)(Adst + head * 64 + dd);
    for (int rr = 0; rr < 4; ++rr) {
        float ps = acc[rr][0] * as4.x + acc[rr][1] * as4.y + acc[rr][2] * as4.z + acc[rr][3] * as4.w;
        float pd = acc[rr][0] * ad4.x + acc[rr][1] * ad4.y + acc[rr][2] * ad4.z + acc[rr][3] * ad4.w;
        for (int m = 1; m < 16; m <<= 1) {
            ps += __shfl_xor(ps, m, 64);
            pd += __shfl_xor(pd, m, 64);
        }
        if ((t & 15) == 0) {
            s_src[(row0 + r0 + rr) * 4 + head] = ps;
            s_dst[(row0 + r0 + rr) * 4 + head] = pd;
        }
    }
}

// ---------- K2: histogram ----------
__global__ void k_hist(const int* __restrict__ dst, int* __restrict__ cnt, int E) {
    int e = blockIdx.x * blockDim.x + threadIdx.x;
    if (e < E) atomicAdd(cnt + dst[e], 1);
}

// ---------- K3a/b/c: two-level exclusive scan ----------
__global__ __launch_bounds__(256) void k_scan1(
    const int* __restrict__ cnt, int* __restrict__ rowptr, int* __restrict__ bsum, int N) {
    __shared__ int wtot[4];
    const int lane = threadIdx.x & 63, wave = threadIdx.x >> 6;
    const int i = blockIdx.x * 256 + threadIdx.x;
    int v = (i < N) ? cnt[i] : 0;
    int x = v;
    for (int off = 1; off < 64; off <<= 1) {
        int y = __shfl_up(x, off, 64);
        if (lane >= off) x += y;
    }
    if (lane == 63) wtot[wave] = x;
    __syncthreads();
    int wo = 0;
    for (int wv = 0; wv < wave; ++wv) wo += wtot[wv];
    if (i < N) rowptr[i] = wo + x - v;
    if (threadIdx.x == 255) bsum[blockIdx.x] = wo + x;
}
__global__ void k_scan2(int* __restrict__ bsum, int nb) {
    const int lane = threadIdx.x;
    int carry = 0;
    for (int base = 0; base < nb; base += 64) {
        int i = base + lane;
        int v = (i < nb) ? bsum[i] : 0;
        int x = v;
        for (int off = 1; off < 64; off <<= 1) {
            int y = __shfl_up(x, off, 64);
            if (lane >= off) x += y;
        }
        if (i < nb) bsum[i] = carry + x - v;
        carry += __shfl(x, 63, 64);
    }
}
__global__ void k_scan3(int* __restrict__ rowptr, const int* __restrict__ bsum,
                        int* __restrict__ wcnt, int N, int E) {
    int i = blockIdx.x * blockDim.x + threadIdx.x;
    if (i < N) {
        int v = rowptr[i] + bsum[i >> 8];
        rowptr[i] = v;
        wcnt[i] = v;
    }
    if (i == N) rowptr[N] = E;
}

// ---------- K4: scatter src ids into CSR order ----------
__global__ void k_scatter(const int* __restrict__ src, const int* __restrict__ dst,
                          int* __restrict__ wcnt, int* __restrict__ esrc, int E) {
    int e = blockIdx.x * blockDim.x + threadIdx.x;
    if (e < E) {
        int pos = atomicAdd(wcnt + dst[e], 1);
        esrc[pos] = src[e];
    }
}

// ---------- K5: per-dst gather-aggregate -> concat (bf16, into d_out); zero LDS ----------
__global__ __launch_bounds__(256) void k_agg(
    const float* __restrict__ s_src, const float* __restrict__ s_dst,
    const unsigned short* __restrict__ h_bf,
    const int* __restrict__ rowptr, const int* __restrict__ esrc,
    unsigned short* __restrict__ concat) {
    const int t = threadIdx.x;
    const int lane = t & 63;
    const int wave = t >> 6;
    const int row0 = blockIdx.x * 16;
    const int head = lane >> 4;
    const int c0 = lane << 2;
    const int eslot = lane & 15;
    const int hsel = lane & 48;

    for (int rr = 0; rr < 4; ++rr) {
        const int n = row0 + wave * 4 + rr;
        const int beg = rowptr[n], end = rowptr[n + 1];
        const float sdst = s_dst[n * 4 + head];
        float num0 = 0, num1 = 0, num2 = 0, num3 = 0, den = 0;
        for (int base = beg; base < end; base += 16) {
            const int nn = end - base;
            int sid = 0;
            float my_ex = 0.0f;
            if (eslot < nn) {
                sid = esrc[base + eslot];
                float v = s_src[sid * 4 + head] + sdst;
                v = v > 0.0f ? v : LEAKY * v;
                my_ex = __expf(v);
            }
#pragma unroll
            for (int e = 0; e < 16; ++e) {
                float ex = __shfl(my_ex, hsel | e, 64);
                int s    = __shfl(sid, e, 64);
                ushort4 hv = *(const ushort4*)(h_bf + (size_t)s * 256 + c0);
                num0 += ex * bf2f(hv.x);
                num1 += ex * bf2f(hv.y);
                num2 += ex * bf2f(hv.z);
                num3 += ex * bf2f(hv.w);
                den  += ex;
            }
        }
        const float inv = 1.0f / (den > 0.0f ? den : 1.0f);
        ushort4 o;
        o.x = f2bf(relu_nan(num0 * inv));
        o.y = f2bf(relu_nan(num1 * inv));
        o.z = f2bf(relu_nan(num2 * inv));
        o.w = f2bf(relu_nan(num3 * inv));
        *(ushort4*)(concat + (size_t)n * 256 + c0) = o;
    }
}

// ---------- K6: tiled MFMA GEMM (m97 structure scaled down) ----------
// C[r][c] = act( sum_k A[r][k]*BT[c][k] + bias[c] ), K=256 fixed, bf16 A/BT.
// BM=128, BN=128, BK=32; 256 threads = 4 waves in 2x2, each 64x64 (4x4 MFMA frags).
// BF16OUT=1: relu + bf16 store (layer1 -> hidden); else raw fp32 store (layer2).
template <int BF16OUT>
__global__ __launch_bounds__(256) void k_gemm(
    const unsigned short* __restrict__ A, const unsigned short* __restrict__ BT,
    const float* __restrict__ bias, unsigned short* __restrict__ Cb,
    float* __restrict__ Cf, int N, int ldout) {
    __shared__ unsigned short As[128 * 32];  // [row][k] 64 B rows
    __shared__ unsigned short Bs[128 * 32];  // [col][k]
    const int t = threadIdx.x;
    const int lane = t & 63;
    const int w = t >> 6;
    const int wy = w >> 1, wx = w & 1;
    const int lm = lane & 15, quad = lane >> 4;
    const int row0 = blockIdx.x * 128;
    const int n0 = blockIdx.y * 128;

    // staging map: issue p (0/1), wave w covers 16 rows; lane: row=(lane>>2), k8=(lane&3)*8
    const int srow = lane >> 2;
    const int sk = (lane & 3) * 8;

    float bias_v[4];
#pragma unroll
    for (int ni = 0; ni < 4; ++ni) bias_v[ni] = bias[n0 + wx * 64 + ni * 16 + lm];

    floatx4 acc[4][4];
#pragma unroll
    for (int mi = 0; mi < 4; ++mi)
#pragma unroll
        for (int ni = 0; ni < 4; ++ni) {
            float b = bias_v[ni];
            acc[mi][ni] = (floatx4){b, b, b, b};
        }

    for (int k0 = 0; k0 < 256; k0 += 32) {
#pragma unroll
        for (int p = 0; p < 2; ++p) {
            int tr = (p * 4 + w) * 16 + srow;
            int ga = row0 + tr; if (ga >= N) ga = N - 1;   // clamp (stores are guarded)
            gload_lds16(A + (size_t)ga * 256 + k0 + sk,
                        (char*)As + (size_t)tr * 64 + sk * 2);
            gload_lds16(BT + (size_t)(n0 + tr) * 256 + k0 + sk,
                        (char*)Bs + (size_t)tr * 64 + sk * 2);
        }
        __syncthreads();
        short8 af[4], bf[4];
#pragma unroll
        for (int mi = 0; mi < 4; ++mi)
            af[mi] = *(const short8*)(As + (size_t)(wy * 64 + mi * 16 + lm) * 32 + quad * 8);
#pragma unroll
        for (int ni = 0; ni < 4; ++ni)
            bf[ni] = *(const short8*)(Bs + (size_t)(wx * 64 + ni * 16 + lm) * 32 + quad * 8);
#pragma unroll
        for (int mi = 0; mi < 4; ++mi)
#pragma unroll
            for (int ni = 0; ni < 4; ++ni)
                acc[mi][ni] = __builtin_amdgcn_mfma_f32_16x16x32_bf16(af[mi], bf[ni], acc[mi][ni], 0, 0, 0);
        __syncthreads();
    }

#pragma unroll
    for (int mi = 0; mi < 4; ++mi)
#pragma unroll
        for (int ni = 0; ni < 4; ++ni)
#pragma unroll
            for (int q = 0; q < 4; ++q) {
                int r = row0 + wy * 64 + mi * 16 + quad * 4 + q;
                int c = n0 + wx * 64 + ni * 16 + lm;
                if (r < N) {
                    if (BF16OUT) Cb[(size_t)r * ldout + c] = f2bf(relu_nan(acc[mi][ni][q]));
                    else         Cf[(size_t)r * ldout + c] = acc[mi][ni][q];
                }
            }
}

extern "C" void kernel_launch(void* const* d_in, const int* in_sizes, int n_in,
                              void* d_out, int out_size, void* d_ws, size_t ws_size,
                              hipStream_t stream) {
    const float* X    = (const float*)d_in[0];
    const int* src    = (const int*)d_in[1];
    const int* dst    = (const int*)d_in[2];
    const float* Wn   = (const float*)d_in[3];
    const float* Asrc = (const float*)d_in[4];
    const float* Adst = (const float*)d_in[5];
    const float* W1   = (const float*)d_in[6];
    const float* b1   = (const float*)d_in[7];
    const float* W2   = (const float*)d_in[8];
    const float* b2   = (const float*)d_in[9];
    float* out = (float*)d_out;

    const int N = in_sizes[0] / 128;   // 50000
    const int E = in_sizes[1];         // 800000
    const int NB = (N + 255) / 256;
    const int NR = (N + 127) / 128;    // GEMM row tiles

    // ws layout (16B-aligned offsets), total ~31.2 MB.
    // h_bf doubles as the MLP hidden buffer after k_agg (same [N,256] bf16 shape).
    size_t off = 0;
    char* w = (char*)d_ws;
    unsigned short* h_bf = (unsigned short*)(w + off); off += (size_t)N * 256 * 2;
    float* s_src = (float*)(w + off);                  off += (size_t)N * 4 * 4;
    float* s_dst = (float*)(w + off);                  off += (size_t)N * 4 * 4;
    int* cnt     = (int*)(w + off);                    off += (size_t)N * 4;
    int* rowptr  = (int*)(w + off);                    off += ((size_t)(N + 1) * 4 + 15) & ~15ull;
    int* wcnt    = (int*)(w + off);                    off += (size_t)N * 4;
    int* bsum    = (int*)(w + off);                    off += ((size_t)NB * 4 + 15) & ~15ull;
    int* esrc    = (int*)(w + off);                    off += (size_t)E * 4;
    unsigned short* W1T = (unsigned short*)(w + off);  off += 256 * 256 * 2;
    unsigned short* W2T = (unsigned short*)(w + off);  off += 128 * 256 * 2;
    const size_t required = off;

    if (ws_size < required) {
        k_fill<<<dim3((out_size + 255) / 256), dim3(256), 0, stream>>>(
            out, (float)(ws_size >> 20), out_size);
        return;
    }

    unsigned short* concat = (unsigned short*)d_out;  // bf16 [N,256], overwritten by gemm2

    k_zero<<<dim3((N + 255) / 256), dim3(256), 0, stream>>>(cnt, N);
    k_transform<<<dim3(N / 16), dim3(256), 0, stream>>>(X, Wn, Asrc, Adst, h_bf, s_src, s_dst);
    k_hist<<<dim3((E + 255) / 256), dim3(256), 0, stream>>>(dst, cnt, E);
    k_scan1<<<dim3(NB), dim3(256), 0, stream>>>(cnt, rowptr, bsum, N);
    k_scan2<<<dim3(1), dim3(64), 0, stream>>>(bsum, NB);
    k_scan3<<<dim3((N + 256) / 256), dim3(256), 0, stream>>>(rowptr, bsum, wcnt, N, E);
    k_scatter<<<dim3((E + 255) / 256), dim3(256), 0, stream>>>(src, dst, wcnt, esrc, E);
    k_convert<<<dim3(256), dim3(256), 0, stream>>>(W1, W1T, 256, 256);
    k_convert<<<dim3(128), dim3(256), 0, stream>>>(W2, W2T, 256, 128);
    k_agg<<<dim3(N / 16), dim3(256), 0, stream>>>(s_src, s_dst, h_bf, rowptr, esrc, concat);
    // layer 1: hidden = relu(concat @ W1 + b1) -> h_bf (reused, k_agg is done with it)
    k_gemm<1><<<dim3(NR, 2), dim3(256), 0, stream>>>(concat, W1T, b1, h_bf, nullptr, N, 256);
    // layer 2: out = hidden @ W2 + b2 -> fp32 into d_out (each row written by its own block
    // strictly after that block consumed... different buffers entirely: reads h_bf, writes d_out)
    k_gemm<0><<<dim3(NR, 1), dim3(256), 0, stream>>>(h_bf, W2T, b2, nullptr, out, N, 128);
}

// Round 10
// 319.294 us; speedup vs baseline: 2.7800x; 1.0777x over previous
//
#include <hip/hip_runtime.h>

#define LEAKY 0.2f

typedef __attribute__((ext_vector_type(8))) short short8;   // 8 bf16 (MFMA A/B frag)
typedef __attribute__((ext_vector_type(4))) float floatx4;  // MFMA C/D frag

__device__ __forceinline__ float bf2f(unsigned short u) {
    return __uint_as_float(((unsigned)u) << 16);
}
__device__ __forceinline__ unsigned short f2bf(float f) {
    unsigned u = __float_as_uint(f);
    unsigned r = (u + 0x7fffu + ((u >> 16) & 1u)) >> 16;  // RNE
    return (unsigned short)r;
}
__device__ __forceinline__ float relu_nan(float v) { return v < 0.0f ? 0.0f : v; }

// async global->LDS, 16 B per lane (dest = wave-uniform base + lane*16)
__device__ __forceinline__ void gload_lds16(const void* g, void* l) {
    __builtin_amdgcn_global_load_lds((const __attribute__((address_space(1))) void*)g,
                                     (__attribute__((address_space(3))) void*)l, 16, 0, 0);
}

// ---------- K_fill ----------
__global__ void k_fill(float* __restrict__ p, float val, int n) {
    int i = blockIdx.x * blockDim.x + threadIdx.x;
    if (i < n) p[i] = val;
}

// ---------- K_zero ----------
__global__ void k_zero(int* __restrict__ cnt, int n) {
    int i = blockIdx.x * blockDim.x + threadIdx.x;
    if (i < n) cnt[i] = 0;
}

// ---------- K_cvt_x: X fp32 -> bf16 (vectorized 4/thread) ----------
__global__ void k_cvt_x(const float* __restrict__ X, unsigned short* __restrict__ Xb, int n4) {
    int i = blockIdx.x * blockDim.x + threadIdx.x;
    if (i < n4) {
        float4 v = ((const float4*)X)[i];
        ushort4 o;
        o.x = f2bf(v.x); o.y = f2bf(v.y); o.z = f2bf(v.z); o.w = f2bf(v.w);
        ((ushort4*)Xb)[i] = o;
    }
}

// ---------- K_cvt_wn: WnT[col][k] = bf16(Wn[head][k][d]), col = head*64+d ----------
__global__ void k_cvt_wn(const float* __restrict__ Wn, unsigned short* __restrict__ WnT) {
    int col = blockIdx.x, k = threadIdx.x;
    int head = col >> 6, d = col & 63;
    WnT[(size_t)col * 128 + k] = f2bf(Wn[(size_t)head * 8192 + (size_t)k * 64 + d]);
}

// ---------- K_convert: WT[n][k] = bf16(W[k][n]) ----------
__global__ void k_convert(const float* __restrict__ W, unsigned short* __restrict__ WT, int R, int C) {
    int k = threadIdx.x, n = blockIdx.x;
    WT[(size_t)n * R + k] = f2bf(W[(size_t)k * C + n]);
}

// ---------- K_scores: s_src/s_dst[n][head] = sum_d h[n][head][d] * a[head][d] ----------
// wave per row; lane covers dims c0=4*lane (head = lane>>4); reduce over 16 lanes/head.
__global__ __launch_bounds__(256) void k_scores(
    const unsigned short* __restrict__ h_bf,
    const float* __restrict__ Asrc, const float* __restrict__ Adst,
    float* __restrict__ s_src, float* __restrict__ s_dst, int N) {
    const int lane = threadIdx.x & 63;
    const int wave = threadIdx.x >> 6;
    const int n = blockIdx.x * 4 + wave;
    if (n >= N) return;
    const int head = lane >> 4;
    const int c0 = lane << 2;
    ushort4 hv = *(const ushort4*)(h_bf + (size_t)n * 256 + c0);
    float4 as = *(const float4*)(Asrc + c0);
    float4 ad = *(const float4*)(Adst + c0);
    float h0 = bf2f(hv.x), h1 = bf2f(hv.y), h2 = bf2f(hv.z), h3 = bf2f(hv.w);
    float ps = h0 * as.x + h1 * as.y + h2 * as.z + h3 * as.w;
    float pd = h0 * ad.x + h1 * ad.y + h2 * ad.z + h3 * ad.w;
    for (int m = 1; m < 16; m <<= 1) {
        ps += __shfl_xor(ps, m, 64);
        pd += __shfl_xor(pd, m, 64);
    }
    if ((lane & 15) == 0) {
        s_src[n * 4 + head] = ps;
        s_dst[n * 4 + head] = pd;
    }
}

// ---------- K2: histogram ----------
__global__ void k_hist(const int* __restrict__ dst, int* __restrict__ cnt, int E) {
    int e = blockIdx.x * blockDim.x + threadIdx.x;
    if (e < E) atomicAdd(cnt + dst[e], 1);
}

// ---------- K3a/b/c: two-level exclusive scan ----------
__global__ __launch_bounds__(256) void k_scan1(
    const int* __restrict__ cnt, int* __restrict__ rowptr, int* __restrict__ bsum, int N) {
    __shared__ int wtot[4];
    const int lane = threadIdx.x & 63, wave = threadIdx.x >> 6;
    const int i = blockIdx.x * 256 + threadIdx.x;
    int v = (i < N) ? cnt[i] : 0;
    int x = v;
    for (int off = 1; off < 64; off <<= 1) {
        int y = __shfl_up(x, off, 64);
        if (lane >= off) x += y;
    }
    if (lane == 63) wtot[wave] = x;
    __syncthreads();
    int wo = 0;
    for (int wv = 0; wv < wave; ++wv) wo += wtot[wv];
    if (i < N) rowptr[i] = wo + x - v;
    if (threadIdx.x == 255) bsum[blockIdx.x] = wo + x;
}
__global__ void k_scan2(int* __restrict__ bsum, int nb) {
    const int lane = threadIdx.x;
    int carry = 0;
    for (int base = 0; base < nb; base += 64) {
        int i = base + lane;
        int v = (i < nb) ? bsum[i] : 0;
        int x = v;
        for (int off = 1; off < 64; off <<= 1) {
            int y = __shfl_up(x, off, 64);
            if (lane >= off) x += y;
        }
        if (i < nb) bsum[i] = carry + x - v;
        carry += __shfl(x, 63, 64);
    }
}
__global__ void k_scan3(int* __restrict__ rowptr, const int* __restrict__ bsum,
                        int* __restrict__ wcnt, int N, int E) {
    int i = blockIdx.x * blockDim.x + threadIdx.x;
    if (i < N) {
        int v = rowptr[i] + bsum[i >> 8];
        rowptr[i] = v;
        wcnt[i] = v;
    }
    if (i == N) rowptr[N] = E;
}

// ---------- K4: scatter src ids into CSR order ----------
__global__ void k_scatter(const int* __restrict__ src, const int* __restrict__ dst,
                          int* __restrict__ wcnt, int* __restrict__ esrc, int E) {
    int e = blockIdx.x * blockDim.x + threadIdx.x;
    if (e < E) {
        int pos = atomicAdd(wcnt + dst[e], 1);
        esrc[pos] = src[e];
    }
}

// ---------- K5: per-dst gather-aggregate -> concat (bf16, into d_out); zero LDS ----------
__global__ __launch_bounds__(256) void k_agg(
    const float* __restrict__ s_src, const float* __restrict__ s_dst,
    const unsigned short* __restrict__ h_bf,
    const int* __restrict__ rowptr, const int* __restrict__ esrc,
    unsigned short* __restrict__ concat) {
    const int t = threadIdx.x;
    const int lane = t & 63;
    const int wave = t >> 6;
    const int row0 = blockIdx.x * 16;
    const int head = lane >> 4;
    const int c0 = lane << 2;
    const int eslot = lane & 15;
    const int hsel = lane & 48;

    for (int rr = 0; rr < 4; ++rr) {
        const int n = row0 + wave * 4 + rr;
        const int beg = rowptr[n], end = rowptr[n + 1];
        const float sdst = s_dst[n * 4 + head];
        float num0 = 0, num1 = 0, num2 = 0, num3 = 0, den = 0;
        for (int base = beg; base < end; base += 16) {
            const int nn = end - base;
            int sid = 0;
            float my_ex = 0.0f;
            if (eslot < nn) {
                sid = esrc[base + eslot];
                float v = s_src[sid * 4 + head] + sdst;
                v = v > 0.0f ? v : LEAKY * v;
                my_ex = __expf(v);
            }
#pragma unroll
            for (int e = 0; e < 16; ++e) {
                float ex = __shfl(my_ex, hsel | e, 64);
                int s    = __shfl(sid, e, 64);
                ushort4 hv = *(const ushort4*)(h_bf + (size_t)s * 256 + c0);
                num0 += ex * bf2f(hv.x);
                num1 += ex * bf2f(hv.y);
                num2 += ex * bf2f(hv.z);
                num3 += ex * bf2f(hv.w);
                den  += ex;
            }
        }
        const float inv = 1.0f / (den > 0.0f ? den : 1.0f);
        ushort4 o;
        o.x = f2bf(relu_nan(num0 * inv));
        o.y = f2bf(relu_nan(num1 * inv));
        o.z = f2bf(relu_nan(num2 * inv));
        o.w = f2bf(relu_nan(num3 * inv));
        *(ushort4*)(concat + (size_t)n * 256 + c0) = o;
    }
}

// ---------- K6: tiled MFMA GEMM, templated on K and epilogue ----------
// C[r][c] = epi( sum_k A[r][k]*BT[c][k] (+ bias) ), bf16 A/BT.
// BM=128, BN=128, BK=32; 4 waves in 2x2, 64x64 each.
// MODE 0: bf16 out, no bias, no relu (node transform h)
// MODE 1: bf16 out, +bias, relu     (MLP layer 1 -> hidden)
// MODE 2: fp32 out, +bias           (MLP layer 2 -> final)
template <int K, int MODE>
__global__ __launch_bounds__(256) void k_gemm(
    const unsigned short* __restrict__ A, const unsigned short* __restrict__ BT,
    const float* __restrict__ bias, unsigned short* __restrict__ Cb,
    float* __restrict__ Cf, int N, int ldout) {
    __shared__ unsigned short As[128 * 32];
    __shared__ unsigned short Bs[128 * 32];
    const int t = threadIdx.x;
    const int lane = t & 63;
    const int w = t >> 6;
    const int wy = w >> 1, wx = w & 1;
    const int lm = lane & 15, quad = lane >> 4;
    const int row0 = blockIdx.x * 128;
    const int n0 = blockIdx.y * 128;
    const int srow = lane >> 2;
    const int sk = (lane & 3) * 8;

    floatx4 acc[4][4];
    if (MODE == 0) {
#pragma unroll
        for (int mi = 0; mi < 4; ++mi)
#pragma unroll
            for (int ni = 0; ni < 4; ++ni) acc[mi][ni] = (floatx4){0, 0, 0, 0};
    } else {
#pragma unroll
        for (int ni = 0; ni < 4; ++ni) {
            float b = bias[n0 + wx * 64 + ni * 16 + lm];
#pragma unroll
            for (int mi = 0; mi < 4; ++mi) acc[mi][ni] = (floatx4){b, b, b, b};
        }
    }

    for (int k0 = 0; k0 < K; k0 += 32) {
#pragma unroll
        for (int p = 0; p < 2; ++p) {
            int tr = (p * 4 + w) * 16 + srow;
            int ga = row0 + tr; if (ga >= N) ga = N - 1;   // clamp (stores guarded)
            gload_lds16(A + (size_t)ga * K + k0 + sk,
                        (char*)As + (size_t)tr * 64 + sk * 2);
            gload_lds16(BT + (size_t)(n0 + tr) * K + k0 + sk,
                        (char*)Bs + (size_t)tr * 64 + sk * 2);
        }
        __syncthreads();
        short8 af[4], bfr[4];
#pragma unroll
        for (int mi = 0; mi < 4; ++mi)
            af[mi] = *(const short8*)(As + (size_t)(wy * 64 + mi * 16 + lm) * 32 + quad * 8);
#pragma unroll
        for (int ni = 0; ni < 4; ++ni)
            bfr[ni] = *(const short8*)(Bs + (size_t)(wx * 64 + ni * 16 + lm) * 32 + quad * 8);
#pragma unroll
        for (int mi = 0; mi < 4; ++mi)
#pragma unroll
            for (int ni = 0; ni < 4; ++ni)
                acc[mi][ni] = __builtin_amdgcn_mfma_f32_16x16x32_bf16(af[mi], bfr[ni], acc[mi][ni], 0, 0, 0);
        __syncthreads();
    }

#pragma unroll
    for (int mi = 0; mi < 4; ++mi)
#pragma unroll
        for (int ni = 0; ni < 4; ++ni)
#pragma unroll
            for (int q = 0; q < 4; ++q) {
                int r = row0 + wy * 64 + mi * 16 + quad * 4 + q;
                int c = n0 + wx * 64 + ni * 16 + lm;
                if (r < N) {
                    if (MODE == 0)      Cb[(size_t)r * ldout + c] = f2bf(acc[mi][ni][q]);
                    else if (MODE == 1) Cb[(size_t)r * ldout + c] = f2bf(relu_nan(acc[mi][ni][q]));
                    else                Cf[(size_t)r * ldout + c] = acc[mi][ni][q];
                }
            }
}

extern "C" void kernel_launch(void* const* d_in, const int* in_sizes, int n_in,
                              void* d_out, int out_size, void* d_ws, size_t ws_size,
                              hipStream_t stream) {
    const float* X    = (const float*)d_in[0];
    const int* src    = (const int*)d_in[1];
    const int* dst    = (const int*)d_in[2];
    const float* Wn   = (const float*)d_in[3];
    const float* Asrc = (const float*)d_in[4];
    const float* Adst = (const float*)d_in[5];
    const float* W1   = (const float*)d_in[6];
    const float* b1   = (const float*)d_in[7];
    const float* W2   = (const float*)d_in[8];
    const float* b2   = (const float*)d_in[9];
    float* out = (float*)d_out;

    const int N = in_sizes[0] / 128;   // 50000
    const int E = in_sizes[1];         // 800000
    const int NB = (N + 255) / 256;
    const int NR = (N + 127) / 128;    // GEMM row tiles

    // ws layout (16B-aligned offsets), ~31.3 MB.
    // h_bf doubles as the MLP hidden buffer after k_agg consumes it.
    size_t off = 0;
    char* w = (char*)d_ws;
    unsigned short* h_bf = (unsigned short*)(w + off); off += (size_t)N * 256 * 2;
    float* s_src = (float*)(w + off);                  off += (size_t)N * 4 * 4;
    float* s_dst = (float*)(w + off);                  off += (size_t)N * 4 * 4;
    int* cnt     = (int*)(w + off);                    off += (size_t)N * 4;
    int* rowptr  = (int*)(w + off);                    off += ((size_t)(N + 1) * 4 + 15) & ~15ull;
    int* wcnt    = (int*)(w + off);                    off += (size_t)N * 4;
    int* bsum    = (int*)(w + off);                    off += ((size_t)NB * 4 + 15) & ~15ull;
    int* esrc    = (int*)(w + off);                    off += (size_t)E * 4;
    unsigned short* W1T = (unsigned short*)(w + off);  off += 256 * 256 * 2;
    unsigned short* W2T = (unsigned short*)(w + off);  off += 128 * 256 * 2;
    unsigned short* WnT = (unsigned short*)(w + off);  off += 256 * 128 * 2;
    const size_t required = off;

    if (ws_size < required) {
        k_fill<<<dim3((out_size + 255) / 256), dim3(256), 0, stream>>>(
            out, (float)(ws_size >> 20), out_size);
        return;
    }

    // d_out staging: Xb (bf16 [N,128]) -> consumed by transform GEMM;
    // then concat (bf16 [N,256]) -> consumed by gemm1; then final fp32 out.
    unsigned short* Xb     = (unsigned short*)d_out;
    unsigned short* concat = (unsigned short*)d_out;

    k_zero<<<dim3((N + 255) / 256), dim3(256), 0, stream>>>(cnt, N);
    k_cvt_x<<<dim3((N * 32 + 255) / 256), dim3(256), 0, stream>>>(X, Xb, N * 32);
    k_cvt_wn<<<dim3(256), dim3(128), 0, stream>>>(Wn, WnT);
    // h = Xb @ WnT  (MFMA, bf16 out, no bias/act)
    k_gemm<128, 0><<<dim3(NR, 2), dim3(256), 0, stream>>>(Xb, WnT, nullptr, h_bf, nullptr, N, 256);
    k_scores<<<dim3((N + 3) / 4), dim3(256), 0, stream>>>(h_bf, Asrc, Adst, s_src, s_dst, N);
    k_hist<<<dim3((E + 255) / 256), dim3(256), 0, stream>>>(dst, cnt, E);
    k_scan1<<<dim3(NB), dim3(256), 0, stream>>>(cnt, rowptr, bsum, N);
    k_scan2<<<dim3(1), dim3(64), 0, stream>>>(bsum, NB);
    k_scan3<<<dim3((N + 256) / 256), dim3(256), 0, stream>>>(rowptr, bsum, wcnt, N, E);
    k_scatter<<<dim3((E + 255) / 256), dim3(256), 0, stream>>>(src, dst, wcnt, esrc, E);
    k_convert<<<dim3(256), dim3(256), 0, stream>>>(W1, W1T, 256, 256);
    k_convert<<<dim3(128), dim3(256), 0, stream>>>(W2, W2T, 256, 128);
    k_agg<<<dim3(N / 16), dim3(256), 0, stream>>>(s_src, s_dst, h_bf, rowptr, esrc, concat);
    // layer 1: hidden = relu(concat @ W1 + b1) -> h_bf (h is dead after k_agg)
    k_gemm<256, 1><<<dim3(NR, 2), dim3(256), 0, stream>>>(concat, W1T, b1, h_bf, nullptr, N, 256);
    // layer 2: out = hidden @ W2 + b2 -> fp32 into d_out
    k_gemm<256, 2><<<dim3(NR, 1), dim3(256), 0, stream>>>(h_bf, W2T, b2, nullptr, out, N, 128);
}